// Round 5
// baseline (717.807 us; speedup 1.0000x reference)
//
#include <hip/hip_runtime.h>
#include <hip/hip_bf16.h>
#include <cstdint>

// MLA: B=2, S=4096, D=1024, H=4, dk=d_kv=256, scale=1/16.
// bf16 MFMA everywhere: QKV fused NT GEMM -> flash attention (K/V shared
// across heads) -> O projection (fp32 out).
// R2: attention 512 threads (2 waves/SIMD); scale folded into Q; defer-max.
// R3: + s_setprio(1) around MFMA clusters (T5).
// R4: 16 waves/block, intra-block t-split (groups of 8 waves handle t-halves
//     of each staged tile with independent softmax state; fp32 LDS merge at
//     end). Grid stays 256 (1 block/CU) but waves/SIMD 2 -> 4.

typedef __bf16 bf16_t;
typedef __bf16 bf16x8 __attribute__((ext_vector_type(8)));
typedef float f32x4 __attribute__((ext_vector_type(4)));
typedef unsigned short u16;
typedef u16 u16x8 __attribute__((ext_vector_type(8)));

#define DEVI static __device__ __forceinline__

constexpr int S_LEN = 4096;
constexpr int NQKV = 1536;   // Q(1024) | K(256) | V(256)
constexpr int DMODEL = 1024;
constexpr int DKV = 256;

DEVI void gload_lds16(const bf16_t* g, bf16_t* l) {
  __builtin_amdgcn_global_load_lds(
      (const __attribute__((address_space(1))) void*)g,
      (__attribute__((address_space(3))) void*)l, 16, 0, 0);
}

// ---------------- fp32 -> bf16 convert (vectorized) ----------------
__global__ void cvt_bf16(const float4* __restrict__ src, bf16_t* __restrict__ dst, int n4) {
  int i = blockIdx.x * 256 + threadIdx.x;
  if (i < n4) {
    float4 v = src[i];
    bf16_t o[4] = { (bf16_t)v.x, (bf16_t)v.y, (bf16_t)v.z, (bf16_t)v.w };
    *reinterpret_cast<uint64_t*>(dst + (size_t)i * 4) = *reinterpret_cast<uint64_t*>(o);
  }
}

// ---------------- NT GEMM: C[M,N] = A[M,K] * Bw[N,K]^T ----------------
template <typename OutT>
__global__ __launch_bounds__(256) void gemm_nt(
    const bf16_t* __restrict__ A, const bf16_t* __restrict__ Bw,
    OutT* __restrict__ C, int M, int N, int K) {
  __shared__ __align__(16) bf16_t lA[2][128 * 32];
  __shared__ __align__(16) bf16_t lB[2][128 * 32];
  const int tid = threadIdx.x;
  const int lane = tid & 63;
  const int w = tid >> 6;
  const int r16 = lane & 15, hi = lane >> 4;
  const int wm = (w >> 1) * 64, wn = (w & 1) * 64;
  const long bm = (long)blockIdx.x * 128;
  const long bn = (long)blockIdx.y * 128;

  f32x4 acc[4][4] = {};

  auto stageAB = [&](int buf, int k0) {
#pragma unroll
    for (int c = 0; c < 2; ++c) {
      const int chunk = w + c * 4;           // 8 chunks of 1KB per tile
      const int row = chunk * 16 + (lane >> 2);
      const int kk = (lane & 3) * 8;
      gload_lds16(A + (bm + row) * (long)K + k0 + kk, &lA[buf][chunk * 512]);
      gload_lds16(Bw + (bn + row) * (long)K + k0 + kk, &lB[buf][chunk * 512]);
    }
  };

  const int nk = K >> 5;
  stageAB(0, 0);
  for (int kt = 0; kt < nk; ++kt) {
    const int cur = kt & 1;
    __syncthreads();
    if (kt + 1 < nk) stageAB(cur ^ 1, (kt + 1) * 32);
    const bf16_t* la = lA[cur];
    const bf16_t* lb = lB[cur];
    bf16x8 af[4], bq[4];
#pragma unroll
    for (int i = 0; i < 4; ++i)
      af[i] = *(const bf16x8*)&la[(wm + i * 16 + r16) * 32 + hi * 8];
#pragma unroll
    for (int j = 0; j < 4; ++j)
      bq[j] = *(const bf16x8*)&lb[(wn + j * 16 + r16) * 32 + hi * 8];
    __builtin_amdgcn_s_setprio(1);
#pragma unroll
    for (int i = 0; i < 4; ++i)
#pragma unroll
      for (int j = 0; j < 4; ++j)
        acc[i][j] = __builtin_amdgcn_mfma_f32_16x16x32_bf16(af[i], bq[j], acc[i][j], 0, 0, 0);
    __builtin_amdgcn_s_setprio(0);
    __syncthreads();
  }

#pragma unroll
  for (int i = 0; i < 4; ++i)
#pragma unroll
    for (int j = 0; j < 4; ++j)
#pragma unroll
      for (int r = 0; r < 4; ++r) {
        long row = bm + wm + i * 16 + hi * 4 + r;
        long col = bn + wn + j * 16 + r16;
        C[row * N + col] = (OutT)acc[i][j][r];
      }
}

// ---------------- V transpose: Vt[b][d][t] = QKV[b*S+t][1280+d] ----------------
__global__ void transpose_v(const bf16_t* __restrict__ QKV, bf16_t* __restrict__ Vt) {
  __shared__ u16 tile[64][68];
  const int t0 = blockIdx.x * 64, d0 = blockIdx.y * 64, b = blockIdx.z;
  const int tid = threadIdx.x;
  const int r = tid >> 3, c8 = tid & 7;
#pragma unroll
  for (int p = 0; p < 2; ++p) {
    const int tr = p * 32 + r;
    const u16* gp = (const u16*)QKV + (size_t)(b * S_LEN + t0 + tr) * NQKV + 1280 + d0 + c8 * 8;
    u16x8 v = *(const u16x8*)gp;
#pragma unroll
    for (int j = 0; j < 8; ++j) tile[tr][c8 * 8 + j] = v[j];
  }
  __syncthreads();
#pragma unroll
  for (int p = 0; p < 2; ++p) {
    const int dr = p * 32 + r;
    u16x8 v;
#pragma unroll
    for (int j = 0; j < 8; ++j) v[j] = tile[c8 * 8 + j][dr];
    *(u16x8*)((u16*)Vt + (size_t)(b * DKV + d0 + dr) * S_LEN + t0 + c8 * 8) = v;
  }
}

// ---------------- Flash attention ----------------
// 256 blocks (bh = id%8 -> XCD-local K/V), 1024 threads = 16 waves.
// Wave w: group grp=w>>3 handles t-cols [grp*32, grp*32+32) of each staged
// 64-t K/V tile; w8=w&7 picks its 16 q-rows. Each group keeps independent
// online-softmax state (m, l, O~); merged in fp32 via LDS at the end.
// K/V double-buffered + XOR-swizzled with inverse-swizzled global source.
// Q pre-scaled by 2^-4. Defer-max (T13, THR=8). setprio around MFMA (T5).
__global__ __launch_bounds__(1024, 1) void mla_attn(
    const bf16_t* __restrict__ QKV, const bf16_t* __restrict__ Vt,
    bf16_t* __restrict__ O) {
  __shared__ __align__(16) char smem[148480];
  bf16_t* lK = (bf16_t*)smem;                    // [2][64*256] swizzled, 64KB
  bf16_t* lV = (bf16_t*)(smem + 65536);          // [2][256*64] swizzled, 64KB
  bf16_t* lP = (bf16_t*)(smem + 131072);         // [128][64] swizzled, 16KB
  float*  xO = (float*)smem;                     // [128][256] epilogue reuse
  float*  xML = (float*)(smem + 147456);         // [128][2]

  const int tid = threadIdx.x, lane = tid & 63, w = tid >> 6;  // w in [0,16)
  const int grp = w >> 3, w8 = w & 7;
  const int r16 = lane & 15, hi = lane >> 4;
  const int bh = blockIdx.x & 7;
  const int b = bh >> 2, h = bh & 3;
  const int q0 = (blockIdx.x >> 3) * 128;

  auto stageK = [&](int buf, int t0) {
#pragma unroll
    for (int c = 0; c < 2; ++c) {
      const int chunk = w * 2 + c;               // 32 chunks of 1KB (2 rows)
      const int row = chunk * 2 + (lane >> 5);
      const int gslot = (lane & 31) ^ (row & 7); // inverse swizzle on source
      gload_lds16(QKV + ((long)(b * S_LEN + t0 + row)) * NQKV + 1024 + gslot * 8,
                  &lK[buf * 16384 + chunk * 512]);
    }
  };
  auto stageV = [&](int buf, int t0) {
#pragma unroll
    for (int c = 0; c < 2; ++c) {
      const int chunk = w * 2 + c;               // 32 chunks of 1KB (8 d-rows)
      const int row = chunk * 8 + (lane >> 3);
      const int gslot = (lane & 7) ^ (row & 7);
      gload_lds16(Vt + ((long)(b * DKV + row)) * S_LEN + t0 + gslot * 8,
                  &lV[buf * 16384 + chunk * 512]);
    }
  };

  // Q fragments: 16 rows/wave (both groups load same rows), pre-scaled 2^-4.
  bf16x8 qa[8];
  {
    const bf16_t* qrow = QKV + ((long)(b * S_LEN + q0 + w8 * 16 + r16)) * NQKV + h * DKV;
#pragma unroll
    for (int ks = 0; ks < 8; ++ks) {
      bf16x8 v = *(const bf16x8*)(qrow + ks * 32 + hi * 8);
#pragma unroll
      for (int j = 0; j < 8; ++j) v[j] = (bf16_t)((float)v[j] * 0.0625f);
      qa[ks] = v;
    }
  }

  f32x4 oacc[16] = {};
  float mr[4], lr[4];
#pragma unroll
  for (int r = 0; r < 4; ++r) { mr[r] = -3.0e38f; lr[r] = 0.f; }

  stageK(0, 0);
  stageV(0, 0);

  const int nst = S_LEN / 64;
  for (int kt = 0; kt < nst; ++kt) {
    const int cur = kt & 1;
    __syncthreads();
    if (kt + 1 < nst) { stageK(cur ^ 1, (kt + 1) * 64); stageV(cur ^ 1, (kt + 1) * 64); }

    // ---- S = Q K^T for this group's 2 t-frags (t = grp*32 .. +32) ----
    f32x4 sf[2] = {};
    const char* kbase = (const char*)(lK + cur * 16384);
    __builtin_amdgcn_s_setprio(1);
#pragma unroll
    for (int tfl = 0; tfl < 2; ++tfl) {
      const int row = (grp * 2 + tfl) * 16 + r16;
      const int rowoff = row * 512;
      const int sw = (row & 7) << 4;
#pragma unroll
      for (int ks = 0; ks < 8; ++ks) {
        bf16x8 kf = *(const bf16x8*)(kbase + rowoff + ((ks * 64 + hi * 16) ^ sw));
        sf[tfl] = __builtin_amdgcn_mfma_f32_16x16x32_bf16(qa[ks], kf, sf[tfl], 0, 0, 0);
      }
    }
    __builtin_amdgcn_s_setprio(0);

    // ---- online softmax, defer-max (lane: rows hi*4+r, col tfl*16+r16) ----
    float mx[4];
    float need = -3.0e38f;
#pragma unroll
    for (int r = 0; r < 4; ++r) {
      float m_ = fmaxf(sf[0][r], sf[1][r]);
      m_ = fmaxf(m_, __shfl_xor(m_, 1));
      m_ = fmaxf(m_, __shfl_xor(m_, 2));
      m_ = fmaxf(m_, __shfl_xor(m_, 4));
      m_ = fmaxf(m_, __shfl_xor(m_, 8));
      mx[r] = m_;
      need = fmaxf(need, m_ - mr[r]);
    }
    if (__any(need > 8.0f)) {            // wave-uniform rescale (rare)
#pragma unroll
      for (int r = 0; r < 4; ++r) {
        float mn = fmaxf(mr[r], mx[r]);
        float al = __expf(mr[r] - mn);
        mr[r] = mn;
        lr[r] *= al;
#pragma unroll
        for (int cf = 0; cf < 16; ++cf) oacc[cf][r] *= al;
      }
    }
    float rs[4] = {0.f, 0.f, 0.f, 0.f};
#pragma unroll
    for (int tfl = 0; tfl < 2; ++tfl) {
#pragma unroll
      for (int r = 0; r < 4; ++r) {
        float p = __expf(sf[tfl][r] - mr[r]);
        rs[r] += p;
        const int qrow = w8 * 16 + hi * 4 + r;
        const int t = (grp * 2 + tfl) * 16 + r16;
        *(bf16_t*)((char*)lP + qrow * 128 + ((t * 2) ^ ((qrow & 7) << 4))) = (bf16_t)p;
      }
    }
#pragma unroll
    for (int r = 0; r < 4; ++r) {
      float s_ = rs[r];
      s_ += __shfl_xor(s_, 1);
      s_ += __shfl_xor(s_, 2);
      s_ += __shfl_xor(s_, 4);
      s_ += __shfl_xor(s_, 8);
      lr[r] += s_;
    }

    // ---- O~ += P V over this group's t-cols (ks = grp; same-wave P) ----
    bf16x8 pa;
    {
      const int qrow = w8 * 16 + r16;
      pa = *(const bf16x8*)((const char*)lP + qrow * 128 + ((grp * 64 + hi * 16) ^ ((qrow & 7) << 4)));
    }
    const char* vbase = (const char*)(lV + cur * 16384);
    __builtin_amdgcn_s_setprio(1);
#pragma unroll
    for (int cf = 0; cf < 16; ++cf) {
      const int vrow = cf * 16 + r16;
      const int vsw = (vrow & 7) << 4;
      bf16x8 vf = *(const bf16x8*)(vbase + vrow * 128 + ((grp * 64 + hi * 16) ^ vsw));
      oacc[cf] = __builtin_amdgcn_mfma_f32_16x16x32_bf16(pa, vf, oacc[cf], 0, 0, 0);
    }
    __builtin_amdgcn_s_setprio(0);
    __syncthreads();
  }

  // ---- merge the two groups' partials (fp32 via LDS), then write O ----
  __syncthreads();                        // loop LDS dead; safe to reuse
  if (grp == 1) {
    if (r16 == 0) {
#pragma unroll
      for (int r = 0; r < 4; ++r) {
        const int row = w8 * 16 + hi * 4 + r;
        xML[row * 2 + 0] = mr[r];
        xML[row * 2 + 1] = lr[r];
      }
    }
#pragma unroll
    for (int cf = 0; cf < 16; ++cf)
#pragma unroll
      for (int r = 0; r < 4; ++r)
        xO[(w8 * 16 + hi * 4 + r) * 256 + cf * 16 + r16] = oacc[cf][r];
  }
  __syncthreads();
  if (grp == 0) {
#pragma unroll
    for (int r = 0; r < 4; ++r) {
      const int row = w8 * 16 + hi * 4 + r;
      const float m1 = xML[row * 2 + 0];
      const float l1 = xML[row * 2 + 1];
      const float mm = fmaxf(mr[r], m1);
      const float a0 = __expf(mr[r] - mm);
      const float a1 = __expf(m1 - mm);
      const float inv = 1.0f / (lr[r] * a0 + l1 * a1);
      const long srow = (long)b * S_LEN + q0 + row;
#pragma unroll
      for (int cf = 0; cf < 16; ++cf) {
        float v = (oacc[cf][r] * a0 + xO[row * 256 + cf * 16 + r16] * a1) * inv;
        O[srow * DMODEL + h * DKV + cf * 16 + r16] = (bf16_t)v;
      }
    }
  }
}

// ---------------- launch ----------------
extern "C" void kernel_launch(void* const* d_in, const int* in_sizes, int n_in,
                              void* d_out, int out_size, void* d_ws, size_t ws_size,
                              hipStream_t stream) {
  (void)in_sizes; (void)n_in; (void)out_size; (void)ws_size;
  const float* X = (const float*)d_in[0];
  const float* Wq = (const float*)d_in[1];
  const float* Wk = (const float*)d_in[2];
  const float* Wv = (const float*)d_in[3];
  const float* Wo = (const float*)d_in[4];
  float* out = (float*)d_out;

  // Workspace layout (peak 49MB). AO aliases Xb: Xb is dead after the QKV GEMM.
  char* ws = (char*)d_ws;
  bf16_t* Xb   = (bf16_t*)(ws);                       // 8192x1024   16MB (phase 1)
  bf16_t* AO   = (bf16_t*)(ws);                       // 8192x1024   16MB (phase 2, aliases Xb)
  bf16_t* Wqkv = (bf16_t*)(ws + (16l << 20));         // 1536x1024    3MB
  bf16_t* Wob  = (bf16_t*)(ws + (19l << 20));         // 1024x1024    2MB
  bf16_t* QKV  = (bf16_t*)(ws + (21l << 20));         // 8192x1536   24MB
  bf16_t* Vt   = (bf16_t*)(ws + (45l << 20));         // 2x256x4096   4MB

  const int M = 2 * S_LEN;  // 8192

  cvt_bf16<<<(M * DMODEL / 4 + 255) / 256, 256, 0, stream>>>((const float4*)X, Xb, M * DMODEL / 4);
  cvt_bf16<<<(DMODEL * DMODEL / 4 + 255) / 256, 256, 0, stream>>>((const float4*)Wq, Wqkv, DMODEL * DMODEL / 4);
  cvt_bf16<<<(DKV * DMODEL / 4 + 255) / 256, 256, 0, stream>>>((const float4*)Wk, Wqkv + 1024 * 1024, DKV * DMODEL / 4);
  cvt_bf16<<<(DKV * DMODEL / 4 + 255) / 256, 256, 0, stream>>>((const float4*)Wv, Wqkv + 1280 * 1024, DKV * DMODEL / 4);
  cvt_bf16<<<(DMODEL * DMODEL / 4 + 255) / 256, 256, 0, stream>>>((const float4*)Wo, Wob, DMODEL * DMODEL / 4);

  gemm_nt<bf16_t><<<dim3(M / 128, NQKV / 128), 256, 0, stream>>>(Xb, Wqkv, QKV, M, NQKV, DMODEL);
  transpose_v<<<dim3(S_LEN / 64, DKV / 64, 2), 256, 0, stream>>>(QKV, Vt);
  mla_attn<<<dim3(S_LEN / 128 * 8), 1024, 0, stream>>>(QKV, Vt, AO);
  gemm_nt<float><<<dim3(M / 128, DMODEL / 128), 256, 0, stream>>>(AO, Wob, out, M, DMODEL, DMODEL);
}

// Round 8
// 469.320 us; speedup vs baseline: 1.5295x; 1.5295x over previous
//
#include <hip/hip_runtime.h>
#include <hip/hip_bf16.h>
#include <cstdint>

// MLA: B=2, S=4096, D=1024, H=4, dk=d_kv=256, scale=1/16.
// bf16 MFMA everywhere: QKV fused NT GEMM -> flash attention (K/V shared
// across heads) -> O projection (fp32 out).
// R2: 2 waves/SIMD; scale folded into Q; defer-max (T13). R3: +setprio (T5).
// R4 FAILED: 16 waves/block spilled oacc (VGPR cap 128 < 96+temps) -> 1.3GB
//     scratch traffic. Lesson: state/wave * waves/SIMD must fit reg pool.
// R5: LDS-BW attack at 2 waves/SIMD: rf=2 (32 q-rows/wave, each kf/vf read
//     feeds 2 MFMA -> frag LDS traffic halves) via t-split waves (4 qg x 2 tg,
//     independent softmax, fp32 merge); swapped QK^T (mfma(kf,qa) -> S^T[t][q])
//     makes softmax reduce lane-local: 4 shuffles/wave/tile instead of 32.
// R6/R7: resubmit (no GPU); layout algebra re-audited, watchdogs defined.

typedef __bf16 bf16_t;
typedef __bf16 bf16x8 __attribute__((ext_vector_type(8)));
typedef float f32x4 __attribute__((ext_vector_type(4)));
typedef unsigned short u16;
typedef u16 u16x8 __attribute__((ext_vector_type(8)));

#define DEVI static __device__ __forceinline__

constexpr int S_LEN = 4096;
constexpr int NQKV = 1536;   // Q(1024) | K(256) | V(256)
constexpr int DMODEL = 1024;
constexpr int DKV = 256;

DEVI void gload_lds16(const bf16_t* g, bf16_t* l) {
  __builtin_amdgcn_global_load_lds(
      (const __attribute__((address_space(1))) void*)g,
      (__attribute__((address_space(3))) void*)l, 16, 0, 0);
}

// ---------------- fp32 -> bf16 convert (vectorized) ----------------
__global__ void cvt_bf16(const float4* __restrict__ src, bf16_t* __restrict__ dst, int n4) {
  int i = blockIdx.x * 256 + threadIdx.x;
  if (i < n4) {
    float4 v = src[i];
    bf16_t o[4] = { (bf16_t)v.x, (bf16_t)v.y, (bf16_t)v.z, (bf16_t)v.w };
    *reinterpret_cast<uint64_t*>(dst + (size_t)i * 4) = *reinterpret_cast<uint64_t*>(o);
  }
}

// ---------------- NT GEMM: C[M,N] = A[M,K] * Bw[N,K]^T ----------------
template <typename OutT>
__global__ __launch_bounds__(256) void gemm_nt(
    const bf16_t* __restrict__ A, const bf16_t* __restrict__ Bw,
    OutT* __restrict__ C, int M, int N, int K) {
  __shared__ __align__(16) bf16_t lA[2][128 * 32];
  __shared__ __align__(16) bf16_t lB[2][128 * 32];
  const int tid = threadIdx.x;
  const int lane = tid & 63;
  const int w = tid >> 6;
  const int r16 = lane & 15, hi = lane >> 4;
  const int wm = (w >> 1) * 64, wn = (w & 1) * 64;
  const long bm = (long)blockIdx.x * 128;
  const long bn = (long)blockIdx.y * 128;

  f32x4 acc[4][4] = {};

  auto stageAB = [&](int buf, int k0) {
#pragma unroll
    for (int c = 0; c < 2; ++c) {
      const int chunk = w + c * 4;           // 8 chunks of 1KB per tile
      const int row = chunk * 16 + (lane >> 2);
      const int kk = (lane & 3) * 8;
      gload_lds16(A + (bm + row) * (long)K + k0 + kk, &lA[buf][chunk * 512]);
      gload_lds16(Bw + (bn + row) * (long)K + k0 + kk, &lB[buf][chunk * 512]);
    }
  };

  const int nk = K >> 5;
  stageAB(0, 0);
  for (int kt = 0; kt < nk; ++kt) {
    const int cur = kt & 1;
    __syncthreads();
    if (kt + 1 < nk) stageAB(cur ^ 1, (kt + 1) * 32);
    const bf16_t* la = lA[cur];
    const bf16_t* lb = lB[cur];
    bf16x8 af[4], bq[4];
#pragma unroll
    for (int i = 0; i < 4; ++i)
      af[i] = *(const bf16x8*)&la[(wm + i * 16 + r16) * 32 + hi * 8];
#pragma unroll
    for (int j = 0; j < 4; ++j)
      bq[j] = *(const bf16x8*)&lb[(wn + j * 16 + r16) * 32 + hi * 8];
    __builtin_amdgcn_s_setprio(1);
#pragma unroll
    for (int i = 0; i < 4; ++i)
#pragma unroll
      for (int j = 0; j < 4; ++j)
        acc[i][j] = __builtin_amdgcn_mfma_f32_16x16x32_bf16(af[i], bq[j], acc[i][j], 0, 0, 0);
    __builtin_amdgcn_s_setprio(0);
    __syncthreads();
  }

#pragma unroll
  for (int i = 0; i < 4; ++i)
#pragma unroll
    for (int j = 0; j < 4; ++j)
#pragma unroll
      for (int r = 0; r < 4; ++r) {
        long row = bm + wm + i * 16 + hi * 4 + r;
        long col = bn + wn + j * 16 + r16;
        C[row * N + col] = (OutT)acc[i][j][r];
      }
}

// ---------------- V transpose: Vt[b][d][t] = QKV[b*S+t][1280+d] ----------------
__global__ void transpose_v(const bf16_t* __restrict__ QKV, bf16_t* __restrict__ Vt) {
  __shared__ u16 tile[64][68];
  const int t0 = blockIdx.x * 64, d0 = blockIdx.y * 64, b = blockIdx.z;
  const int tid = threadIdx.x;
  const int r = tid >> 3, c8 = tid & 7;
#pragma unroll
  for (int p = 0; p < 2; ++p) {
    const int tr = p * 32 + r;
    const u16* gp = (const u16*)QKV + (size_t)(b * S_LEN + t0 + tr) * NQKV + 1280 + d0 + c8 * 8;
    u16x8 v = *(const u16x8*)gp;
#pragma unroll
    for (int j = 0; j < 8; ++j) tile[tr][c8 * 8 + j] = v[j];
  }
  __syncthreads();
#pragma unroll
  for (int p = 0; p < 2; ++p) {
    const int dr = p * 32 + r;
    u16x8 v;
#pragma unroll
    for (int j = 0; j < 8; ++j) v[j] = tile[c8 * 8 + j][dr];
    *(u16x8*)((u16*)Vt + (size_t)(b * DKV + d0 + dr) * S_LEN + t0 + c8 * 8) = v;
  }
}

// ---------------- Flash attention ----------------
// 256 blocks (bh = id%8 -> XCD-local K/V), 512 threads = 8 waves = 2/SIMD.
// Wave w: qg = w&3 owns q-rows [qg*32, qg*32+32) (rf=2 frags of 16);
//         tg = w>>2 owns t-cols [tg*32, tg*32+32) of each staged 64-t tile.
// Swapped QK^T: sf = mfma(kf, qa) -> S^T[t][q] (col=q=lane&15) so the
// softmax row-reduce is lane-local + 2 shfls. Independent (m,l,O~) per tg,
// fp32 LDS merge at the end.
// K/V double-buffered + XOR-swizzled, inverse-swizzled global source.
// Q pre-scaled 2^-4. Defer-max (T13, THR=8). setprio around MFMA (T5).
__global__ __launch_bounds__(512, 2) void mla_attn(
    const bf16_t* __restrict__ QKV, const bf16_t* __restrict__ Vt,
    bf16_t* __restrict__ O) {
  __shared__ __align__(16) char smem[147456];       // 144KB
  bf16_t* lK = (bf16_t*)smem;                       // [2][64*256] swizzled 64KB
  bf16_t* lV = (bf16_t*)(smem + 65536);             // [2][256*64] swizzled 64KB
  bf16_t* lP = (bf16_t*)(smem + 131072);            // [128][64]  swizzled 16KB
  float*  xO = (float*)smem;                        // [128][256] epilogue 128KB
  float*  xML = (float*)(smem + 131072);            // [128][2]   epilogue 1KB

  const int tid = threadIdx.x, lane = tid & 63, w = tid >> 6;  // w in [0,8)
  const int qg = w & 3, tg = w >> 2;
  const int r16 = lane & 15, hi = lane >> 4;
  const int bh = blockIdx.x & 7;
  const int b = bh >> 2, h = bh & 3;
  const int q0 = (blockIdx.x >> 3) * 128;

  auto stageK = [&](int buf, int t0) {
#pragma unroll
    for (int c = 0; c < 4; ++c) {
      const int chunk = w * 4 + c;               // 32 chunks of 1KB (2 rows)
      const int row = chunk * 2 + (lane >> 5);
      const int gslot = (lane & 31) ^ (row & 7); // inverse swizzle on source
      gload_lds16(QKV + ((long)(b * S_LEN + t0 + row)) * NQKV + 1024 + gslot * 8,
                  &lK[buf * 16384 + chunk * 512]);
    }
  };
  auto stageV = [&](int buf, int t0) {
#pragma unroll
    for (int c = 0; c < 4; ++c) {
      const int chunk = w * 4 + c;               // 32 chunks of 1KB (8 d-rows)
      const int row = chunk * 8 + (lane >> 3);
      const int gslot = (lane & 7) ^ (row & 7);
      gload_lds16(Vt + ((long)(b * DKV + row)) * S_LEN + t0 + gslot * 8,
                  &lV[buf * 16384 + chunk * 512]);
    }
  };

  // Q fragments: 32 rows/wave (rf=2), pre-scaled 2^-4. B-operand layout.
  bf16x8 qa[2][8];
#pragma unroll
  for (int rf = 0; rf < 2; ++rf) {
    const bf16_t* qrow = QKV + ((long)(b * S_LEN + q0 + qg * 32 + rf * 16 + r16)) * NQKV + h * DKV;
#pragma unroll
    for (int ks = 0; ks < 8; ++ks) {
      bf16x8 v = *(const bf16x8*)(qrow + ks * 32 + hi * 8);
#pragma unroll
      for (int j = 0; j < 8; ++j) v[j] = (bf16_t)((float)v[j] * 0.0625f);
      qa[rf][ks] = v;
    }
  }

  f32x4 oacc[2][16] = {};        // [rf][cf]: row q = qg*32+rf*16+hi*4+reg, col d = cf*16+r16
  float mr[2], lr[2];            // sf-space: per (rf, q=r16)
  mr[0] = mr[1] = -3.0e38f; lr[0] = lr[1] = 0.f;

  stageK(0, 0);
  stageV(0, 0);

  const int nst = S_LEN / 64;
  for (int kt = 0; kt < nst; ++kt) {
    const int cur = kt & 1;
    __syncthreads();
    if (kt + 1 < nst) { stageK(cur ^ 1, (kt + 1) * 64); stageV(cur ^ 1, (kt + 1) * 64); }

    // ---- S^T = K Q^T for this tg's 2 t-frags: col=q=r16, row t=hi*4+reg ----
    f32x4 sf[2][2] = {};         // [rf][tfl]
    const char* kbase = (const char*)(lK + cur * 16384);
    __builtin_amdgcn_s_setprio(1);
#pragma unroll
    for (int tfl = 0; tfl < 2; ++tfl) {
      const int row = (tg * 2 + tfl) * 16 + r16;
      const int rowoff = row * 512;
      const int sw = (row & 7) << 4;
#pragma unroll
      for (int ks = 0; ks < 8; ++ks) {
        bf16x8 kf = *(const bf16x8*)(kbase + rowoff + ((ks * 64 + hi * 16) ^ sw));
        sf[0][tfl] = __builtin_amdgcn_mfma_f32_16x16x32_bf16(kf, qa[0][ks], sf[0][tfl], 0, 0, 0);
        sf[1][tfl] = __builtin_amdgcn_mfma_f32_16x16x32_bf16(kf, qa[1][ks], sf[1][tfl], 0, 0, 0);
      }
    }
    __builtin_amdgcn_s_setprio(0);

    // ---- softmax: lane-local over 8 t-vals + 2 shfls across hi ----
    float mx[2];
#pragma unroll
    for (int rf = 0; rf < 2; ++rf) {
      float m_ = fmaxf(fmaxf(fmaxf(sf[rf][0][0], sf[rf][0][1]), fmaxf(sf[rf][0][2], sf[rf][0][3])),
                       fmaxf(fmaxf(sf[rf][1][0], sf[rf][1][1]), fmaxf(sf[rf][1][2], sf[rf][1][3])));
      m_ = fmaxf(m_, __shfl_xor(m_, 16));
      m_ = fmaxf(m_, __shfl_xor(m_, 32));
      mx[rf] = m_;
    }
    const float need = fmaxf(mx[0] - mr[0], mx[1] - mr[1]);
    if (__any(need > 8.0f)) {            // rare: full rescale
#pragma unroll
      for (int rf = 0; rf < 2; ++rf) {
        const float mn = fmaxf(mr[rf], mx[rf]);
        const float al = __expf(mr[rf] - mn);
        mr[rf] = mn;
        lr[rf] *= al;
#pragma unroll
        for (int r = 0; r < 4; ++r) {
          const float a = __shfl(al, hi * 4 + r);  // al for oacc-row q=hi*4+r
#pragma unroll
          for (int cf = 0; cf < 16; ++cf) oacc[rf][cf][r] *= a;
        }
      }
    }
#pragma unroll
    for (int rf = 0; rf < 2; ++rf) {
      float rs = 0.f;
      const int qrow = qg * 32 + rf * 16 + r16;
      const int qsw = (qrow & 7) << 4;
#pragma unroll
      for (int tfl = 0; tfl < 2; ++tfl) {
#pragma unroll
        for (int r = 0; r < 4; ++r) {
          const float p = __expf(sf[rf][tfl][r] - mr[rf]);
          rs += p;
          const int t = (tg * 2 + tfl) * 16 + hi * 4 + r;
          *(bf16_t*)((char*)lP + qrow * 128 + ((t * 2) ^ qsw)) = (bf16_t)p;
        }
      }
      rs += __shfl_xor(rs, 16);
      rs += __shfl_xor(rs, 32);
      lr[rf] += rs;
    }

    // ---- O~ += P V over this tg's t-half (same-wave P; DS in-order) ----
    bf16x8 pa[2];
#pragma unroll
    for (int rf = 0; rf < 2; ++rf) {
      const int qrow = qg * 32 + rf * 16 + r16;
      pa[rf] = *(const bf16x8*)((const char*)lP + qrow * 128 + ((tg * 64 + hi * 16) ^ ((qrow & 7) << 4)));
    }
    const char* vbase = (const char*)(lV + cur * 16384);
    __builtin_amdgcn_s_setprio(1);
#pragma unroll
    for (int cf = 0; cf < 16; ++cf) {
      const int vrow = cf * 16 + r16;
      const int vsw = (vrow & 7) << 4;
      bf16x8 vf = *(const bf16x8*)(vbase + vrow * 128 + ((tg * 64 + hi * 16) ^ vsw));
      oacc[0][cf] = __builtin_amdgcn_mfma_f32_16x16x32_bf16(pa[0], vf, oacc[0][cf], 0, 0, 0);
      oacc[1][cf] = __builtin_amdgcn_mfma_f32_16x16x32_bf16(pa[1], vf, oacc[1][cf], 0, 0, 0);
    }
    __builtin_amdgcn_s_setprio(0);
    __syncthreads();
  }

  // ---- merge tg=0/1 partials (fp32 via LDS), write O ----
  // loop's final barrier means all reads of lK/lV are done; reuse as xO.
  if (tg == 1) {
#pragma unroll
    for (int rf = 0; rf < 2; ++rf) {
      if (hi == 0) {
        const int row = qg * 32 + rf * 16 + r16;
        xML[row * 2 + 0] = mr[rf];
        xML[row * 2 + 1] = lr[rf];
      }
#pragma unroll
      for (int cf = 0; cf < 16; ++cf)
#pragma unroll
        for (int r = 0; r < 4; ++r)
          xO[(qg * 32 + rf * 16 + hi * 4 + r) * 256 + cf * 16 + r16] = oacc[rf][cf][r];
    }
  }
  __syncthreads();
  if (tg == 0) {
#pragma unroll
    for (int rf = 0; rf < 2; ++rf) {
#pragma unroll
      for (int r = 0; r < 4; ++r) {
        const int row = qg * 32 + rf * 16 + hi * 4 + r;
        const float m0 = __shfl(mr[rf], hi * 4 + r);
        const float l0 = __shfl(lr[rf], hi * 4 + r);
        const float m1 = xML[row * 2 + 0];
        const float l1 = xML[row * 2 + 1];
        const float mm = fmaxf(m0, m1);
        const float a0 = __expf(m0 - mm);
        const float a1 = __expf(m1 - mm);
        const float inv = 1.0f / (l0 * a0 + l1 * a1);
        const long srow = (long)b * S_LEN + q0 + row;
#pragma unroll
        for (int cf = 0; cf < 16; ++cf) {
          float v = (oacc[rf][cf][r] * a0 + xO[row * 256 + cf * 16 + r16] * a1) * inv;
          O[srow * DMODEL + h * DKV + cf * 16 + r16] = (bf16_t)v;
        }
      }
    }
  }
}

// ---------------- launch ----------------
extern "C" void kernel_launch(void* const* d_in, const int* in_sizes, int n_in,
                              void* d_out, int out_size, void* d_ws, size_t ws_size,
                              hipStream_t stream) {
  (void)in_sizes; (void)n_in; (void)out_size; (void)ws_size;
  const float* X = (const float*)d_in[0];
  const float* Wq = (const float*)d_in[1];
  const float* Wk = (const float*)d_in[2];
  const float* Wv = (const float*)d_in[3];
  const float* Wo = (const float*)d_in[4];
  float* out = (float*)d_out;

  // Workspace layout (peak 49MB). AO aliases Xb: Xb is dead after the QKV GEMM.
  char* ws = (char*)d_ws;
  bf16_t* Xb   = (bf16_t*)(ws);                       // 8192x1024   16MB (phase 1)
  bf16_t* AO   = (bf16_t*)(ws);                       // 8192x1024   16MB (phase 2, aliases Xb)
  bf16_t* Wqkv = (bf16_t*)(ws + (16l << 20));         // 1536x1024    3MB
  bf16_t* Wob  = (bf16_t*)(ws + (19l << 20));         // 1024x1024    2MB
  bf16_t* QKV  = (bf16_t*)(ws + (21l << 20));         // 8192x1536   24MB
  bf16_t* Vt   = (bf16_t*)(ws + (45l << 20));         // 2x256x4096   4MB

  const int M = 2 * S_LEN;  // 8192

  cvt_bf16<<<(M * DMODEL / 4 + 255) / 256, 256, 0, stream>>>((const float4*)X, Xb, M * DMODEL / 4);
  cvt_bf16<<<(DMODEL * DMODEL / 4 + 255) / 256, 256, 0, stream>>>((const float4*)Wq, Wqkv, DMODEL * DMODEL / 4);
  cvt_bf16<<<(DKV * DMODEL / 4 + 255) / 256, 256, 0, stream>>>((const float4*)Wk, Wqkv + 1024 * 1024, DKV * DMODEL / 4);
  cvt_bf16<<<(DKV * DMODEL / 4 + 255) / 256, 256, 0, stream>>>((const float4*)Wv, Wqkv + 1280 * 1024, DKV * DMODEL / 4);
  cvt_bf16<<<(DMODEL * DMODEL / 4 + 255) / 256, 256, 0, stream>>>((const float4*)Wo, Wob, DMODEL * DMODEL / 4);

  gemm_nt<bf16_t><<<dim3(M / 128, NQKV / 128), 256, 0, stream>>>(Xb, Wqkv, QKV, M, NQKV, DMODEL);
  transpose_v<<<dim3(S_LEN / 64, DKV / 64, 2), 256, 0, stream>>>(QKV, Vt);
  mla_attn<<<dim3(S_LEN / 128 * 8), 512, 0, stream>>>(QKV, Vt, AO);
  gemm_nt<float><<<dim3(M / 128, DMODEL / 128), 256, 0, stream>>>(AO, Wob, out, M, DMODEL, DMODEL);
}

// Round 11
// 441.022 us; speedup vs baseline: 1.6276x; 1.0642x over previous
//
#include <hip/hip_runtime.h>
#include <hip/hip_bf16.h>
#include <cstdint>

// MLA: B=2, S=4096, D=1024, H=4, dk=d_kv=256, scale=1/16.
// bf16 MFMA everywhere: QKV fused NT GEMM -> flash attention (K/V shared
// across heads) -> O projection (fp32 out).
// R2: 2 waves/SIMD; scale folded into Q; defer-max (T13). R3: +setprio (T5).
// R4 FAILED: 16 waves/block -> VGPR cap 128 -> oacc spill, 1.3GB scratch.
// R5 FAILED: rf=2 needed 256 unified regs (128 VGPR + 128 AGPR) -> partial
//     spill, both pipes' util fell 28%. Lesson: persistent+temps must fit.
// R8: revert to R3 per-wave shape (16 q-rows, rf=1, ~104 VGPR) and attack
//     the stall with 2 DESYNCED blocks/CU: QBLK=64 (4 waves), KVBLK=32,
//     LDS 72KB (lV packed 2 d-rows per 128B row to keep 3-bit XOR swizzle).
//     Grid 512. While block A drains vmcnt(0) at its barrier, block B's
//     waves keep the MFMA pipe fed (m114 cross-wave overlap).
// R9/R10: resubmit (no GPU); packing/swizzle algebra re-audited, watchdogs set.

typedef __bf16 bf16_t;
typedef __bf16 bf16x8 __attribute__((ext_vector_type(8)));
typedef float f32x4 __attribute__((ext_vector_type(4)));
typedef unsigned short u16;
typedef u16 u16x8 __attribute__((ext_vector_type(8)));

#define DEVI static __device__ __forceinline__

constexpr int S_LEN = 4096;
constexpr int NQKV = 1536;   // Q(1024) | K(256) | V(256)
constexpr int DMODEL = 1024;
constexpr int DKV = 256;

DEVI void gload_lds16(const bf16_t* g, bf16_t* l) {
  __builtin_amdgcn_global_load_lds(
      (const __attribute__((address_space(1))) void*)g,
      (__attribute__((address_space(3))) void*)l, 16, 0, 0);
}

// ---------------- fp32 -> bf16 convert (vectorized) ----------------
__global__ void cvt_bf16(const float4* __restrict__ src, bf16_t* __restrict__ dst, int n4) {
  int i = blockIdx.x * 256 + threadIdx.x;
  if (i < n4) {
    float4 v = src[i];
    bf16_t o[4] = { (bf16_t)v.x, (bf16_t)v.y, (bf16_t)v.z, (bf16_t)v.w };
    *reinterpret_cast<uint64_t*>(dst + (size_t)i * 4) = *reinterpret_cast<uint64_t*>(o);
  }
}

// ---------------- NT GEMM: C[M,N] = A[M,K] * Bw[N,K]^T ----------------
template <typename OutT>
__global__ __launch_bounds__(256) void gemm_nt(
    const bf16_t* __restrict__ A, const bf16_t* __restrict__ Bw,
    OutT* __restrict__ C, int M, int N, int K) {
  __shared__ __align__(16) bf16_t lA[2][128 * 32];
  __shared__ __align__(16) bf16_t lB[2][128 * 32];
  const int tid = threadIdx.x;
  const int lane = tid & 63;
  const int w = tid >> 6;
  const int r16 = lane & 15, hi = lane >> 4;
  const int wm = (w >> 1) * 64, wn = (w & 1) * 64;
  const long bm = (long)blockIdx.x * 128;
  const long bn = (long)blockIdx.y * 128;

  f32x4 acc[4][4] = {};

  auto stageAB = [&](int buf, int k0) {
#pragma unroll
    for (int c = 0; c < 2; ++c) {
      const int chunk = w + c * 4;           // 8 chunks of 1KB per tile
      const int row = chunk * 16 + (lane >> 2);
      const int kk = (lane & 3) * 8;
      gload_lds16(A + (bm + row) * (long)K + k0 + kk, &lA[buf][chunk * 512]);
      gload_lds16(Bw + (bn + row) * (long)K + k0 + kk, &lB[buf][chunk * 512]);
    }
  };

  const int nk = K >> 5;
  stageAB(0, 0);
  for (int kt = 0; kt < nk; ++kt) {
    const int cur = kt & 1;
    __syncthreads();
    if (kt + 1 < nk) stageAB(cur ^ 1, (kt + 1) * 32);
    const bf16_t* la = lA[cur];
    const bf16_t* lb = lB[cur];
    bf16x8 af[4], bq[4];
#pragma unroll
    for (int i = 0; i < 4; ++i)
      af[i] = *(const bf16x8*)&la[(wm + i * 16 + r16) * 32 + hi * 8];
#pragma unroll
    for (int j = 0; j < 4; ++j)
      bq[j] = *(const bf16x8*)&lb[(wn + j * 16 + r16) * 32 + hi * 8];
    __builtin_amdgcn_s_setprio(1);
#pragma unroll
    for (int i = 0; i < 4; ++i)
#pragma unroll
      for (int j = 0; j < 4; ++j)
        acc[i][j] = __builtin_amdgcn_mfma_f32_16x16x32_bf16(af[i], bq[j], acc[i][j], 0, 0, 0);
    __builtin_amdgcn_s_setprio(0);
    __syncthreads();
  }

#pragma unroll
  for (int i = 0; i < 4; ++i)
#pragma unroll
    for (int j = 0; j < 4; ++j)
#pragma unroll
      for (int r = 0; r < 4; ++r) {
        long row = bm + wm + i * 16 + hi * 4 + r;
        long col = bn + wn + j * 16 + r16;
        C[row * N + col] = (OutT)acc[i][j][r];
      }
}

// ---------------- V transpose: Vt[b][d][t] = QKV[b*S+t][1280+d] ----------------
__global__ void transpose_v(const bf16_t* __restrict__ QKV, bf16_t* __restrict__ Vt) {
  __shared__ u16 tile[64][68];
  const int t0 = blockIdx.x * 64, d0 = blockIdx.y * 64, b = blockIdx.z;
  const int tid = threadIdx.x;
  const int r = tid >> 3, c8 = tid & 7;
#pragma unroll
  for (int p = 0; p < 2; ++p) {
    const int tr = p * 32 + r;
    const u16* gp = (const u16*)QKV + (size_t)(b * S_LEN + t0 + tr) * NQKV + 1280 + d0 + c8 * 8;
    u16x8 v = *(const u16x8*)gp;
#pragma unroll
    for (int j = 0; j < 8; ++j) tile[tr][c8 * 8 + j] = v[j];
  }
  __syncthreads();
#pragma unroll
  for (int p = 0; p < 2; ++p) {
    const int dr = p * 32 + r;
    u16x8 v;
#pragma unroll
    for (int j = 0; j < 8; ++j) v[j] = tile[c8 * 8 + j][dr];
    *(u16x8*)((u16*)Vt + (size_t)(b * DKV + d0 + dr) * S_LEN + t0 + c8 * 8) = v;
  }
}

// ---------------- Flash attention ----------------
// 512 blocks (bh = id%8 -> XCD-local K/V), 256 threads = 4 waves; 72KB LDS
// -> 2 independent blocks/CU (desynced barriers = latency overlap).
// Wave w owns q-rows [w*16, w*16+16). KVBLK=32 t per tile, double-buffered.
// lK: [32 t][512B], XOR-swizzled (byte ^= (t&7)<<4), inverse-swizzled source.
// lV: packed [R=d>>1][128B] (2 d-rows per 128B row) so the 3-bit XOR swizzle
//     (byte ^= (R&7)<<4) applies; source pre-swizzled to match.
// lP: [64 q][128B] swizzled; same-wave write->read (DS in-order, no barrier).
// Q pre-scaled 2^-4. Defer-max (T13, THR=8). setprio around MFMA (T5).
__global__ __launch_bounds__(256, 2) void mla_attn(
    const bf16_t* __restrict__ QKV, const bf16_t* __restrict__ Vt,
    bf16_t* __restrict__ O) {
  __shared__ __align__(16) bf16_t lK[2][32 * 256];   // 16KB each
  __shared__ __align__(16) bf16_t lV[2][128 * 64];   // 16KB each (packed)
  __shared__ __align__(16) bf16_t lP[64 * 64];       // 8KB

  const int tid = threadIdx.x, lane = tid & 63, w = tid >> 6;  // w in [0,4)
  const int r16 = lane & 15, hi = lane >> 4;
  const int bh = blockIdx.x & 7;          // XCD-locality: same (b,h) -> same XCD
  const int b = bh >> 2, h = bh & 3;
  const int q0 = (blockIdx.x >> 3) * 64;

  auto stageK = [&](int buf, int t0) {
#pragma unroll
    for (int c = 0; c < 4; ++c) {
      const int chunk = w * 4 + c;               // 16 chunks of 1KB (2 t-rows)
      const int row = chunk * 2 + (lane >> 5);
      const int gslot = (lane & 31) ^ (row & 7); // inverse swizzle on source
      gload_lds16(QKV + ((long)(b * S_LEN + t0 + row)) * NQKV + 1024 + gslot * 8,
                  &lK[buf][chunk * 512]);
    }
  };
  auto stageV = [&](int buf, int t0) {
#pragma unroll
    for (int c = 0; c < 4; ++c) {
      const int chunk = w * 4 + c;               // 16 chunks of 1KB (8 lds-rows)
      const int R = chunk * 8 + (lane >> 3);     // lds row = d>>1
      const int gslot = (lane & 7) ^ (R & 7);    // inverse swizzle on source
      const int d = 2 * R + (gslot >> 2);
      gload_lds16(Vt + ((long)(b * DKV + d)) * S_LEN + t0 + (gslot & 3) * 8,
                  &lV[buf][chunk * 512]);
    }
  };

  // Q fragments in registers: 16 rows/wave, full dk=256; pre-scale by 2^-4.
  bf16x8 qa[8];
  {
    const bf16_t* qrow = QKV + ((long)(b * S_LEN + q0 + w * 16 + r16)) * NQKV + h * DKV;
#pragma unroll
    for (int ks = 0; ks < 8; ++ks) {
      bf16x8 v = *(const bf16x8*)(qrow + ks * 32 + hi * 8);
#pragma unroll
      for (int j = 0; j < 8; ++j) v[j] = (bf16_t)((float)v[j] * 0.0625f);
      qa[ks] = v;
    }
  }

  f32x4 oacc[16] = {};
  float mr[4], lr[4];
#pragma unroll
  for (int r = 0; r < 4; ++r) { mr[r] = -3.0e38f; lr[r] = 0.f; }

  stageK(0, 0);
  stageV(0, 0);

  const int nst = S_LEN / 32;
  for (int kt = 0; kt < nst; ++kt) {
    const int cur = kt & 1;
    __syncthreads();
    if (kt + 1 < nst) { stageK(cur ^ 1, (kt + 1) * 32); stageV(cur ^ 1, (kt + 1) * 32); }

    // ---- S = Q K^T (rows q, cols t); Q pre-scaled ----
    f32x4 sf[2] = {};
    const char* kbase = (const char*)lK[cur];
    __builtin_amdgcn_s_setprio(1);
#pragma unroll
    for (int tf = 0; tf < 2; ++tf) {
      const int row = tf * 16 + r16;
      const int rowoff = row * 512;
      const int sw = (row & 7) << 4;
#pragma unroll
      for (int ks = 0; ks < 8; ++ks) {
        bf16x8 kf = *(const bf16x8*)(kbase + rowoff + ((ks * 64 + hi * 16) ^ sw));
        sf[tf] = __builtin_amdgcn_mfma_f32_16x16x32_bf16(qa[ks], kf, sf[tf], 0, 0, 0);
      }
    }
    __builtin_amdgcn_s_setprio(0);

    // ---- online softmax, defer-max (lane: rows hi*4+r, col tf*16+r16) ----
    float mx[4];
    float need = -3.0e38f;
#pragma unroll
    for (int r = 0; r < 4; ++r) {
      float m_ = fmaxf(sf[0][r], sf[1][r]);
      m_ = fmaxf(m_, __shfl_xor(m_, 1));
      m_ = fmaxf(m_, __shfl_xor(m_, 2));
      m_ = fmaxf(m_, __shfl_xor(m_, 4));
      m_ = fmaxf(m_, __shfl_xor(m_, 8));
      mx[r] = m_;
      need = fmaxf(need, m_ - mr[r]);
    }
    if (__any(need > 8.0f)) {            // wave-uniform rescale (rare)
#pragma unroll
      for (int r = 0; r < 4; ++r) {
        float mn = fmaxf(mr[r], mx[r]);
        float al = __expf(mr[r] - mn);
        mr[r] = mn;
        lr[r] *= al;
#pragma unroll
        for (int cf = 0; cf < 16; ++cf) oacc[cf][r] *= al;
      }
    }
    float rs[4] = {0.f, 0.f, 0.f, 0.f};
#pragma unroll
    for (int tf = 0; tf < 2; ++tf) {
#pragma unroll
      for (int r = 0; r < 4; ++r) {
        float p = __expf(sf[tf][r] - mr[r]);
        rs[r] += p;
        const int qrow = w * 16 + hi * 4 + r;
        const int t = tf * 16 + r16;
        *(bf16_t*)((char*)lP + qrow * 128 + ((t * 2) ^ ((qrow & 7) << 4))) = (bf16_t)p;
      }
    }
#pragma unroll
    for (int r = 0; r < 4; ++r) {
      float s_ = rs[r];
      s_ += __shfl_xor(s_, 1);
      s_ += __shfl_xor(s_, 2);
      s_ += __shfl_xor(s_, 4);
      s_ += __shfl_xor(s_, 8);
      lr[r] += s_;
    }

    // ---- O += P V  (P via lP re-layout; same-wave rows, DS in-order) ----
    bf16x8 pa;
    {
      const int qrow = w * 16 + r16;
      pa = *(const bf16x8*)((const char*)lP + qrow * 128 + ((hi * 16) ^ ((qrow & 7) << 4)));
    }
    const char* vbase = (const char*)lV[cur];
    __builtin_amdgcn_s_setprio(1);
#pragma unroll
    for (int cf = 0; cf < 16; ++cf) {
      const int vrow = cf * 16 + r16;
      const int R = vrow >> 1;
      bf16x8 vf = *(const bf16x8*)(vbase + R * 128 + ((((vrow & 1) * 64) + hi * 16) ^ ((R & 7) << 4)));
      oacc[cf] = __builtin_amdgcn_mfma_f32_16x16x32_bf16(pa, vf, oacc[cf], 0, 0, 0);
    }
    __builtin_amdgcn_s_setprio(0);
    __syncthreads();
  }

  // epilogue: normalize, write per-head slice of [B*S, 1024]
  {
    float inv[4];
#pragma unroll
    for (int r = 0; r < 4; ++r) inv[r] = 1.0f / lr[r];
#pragma unroll
    for (int cf = 0; cf < 16; ++cf)
#pragma unroll
      for (int r = 0; r < 4; ++r) {
        const long srow = (long)b * S_LEN + q0 + w * 16 + hi * 4 + r;
        O[srow * DMODEL + h * DKV + cf * 16 + r16] = (bf16_t)(oacc[cf][r] * inv[r]);
      }
  }
}

// ---------------- launch ----------------
extern "C" void kernel_launch(void* const* d_in, const int* in_sizes, int n_in,
                              void* d_out, int out_size, void* d_ws, size_t ws_size,
                              hipStream_t stream) {
  (void)in_sizes; (void)n_in; (void)out_size; (void)ws_size;
  const float* X = (const float*)d_in[0];
  const float* Wq = (const float*)d_in[1];
  const float* Wk = (const float*)d_in[2];
  const float* Wv = (const float*)d_in[3];
  const float* Wo = (const float*)d_in[4];
  float* out = (float*)d_out;

  // Workspace layout (peak 49MB). AO aliases Xb: Xb is dead after the QKV GEMM.
  char* ws = (char*)d_ws;
  bf16_t* Xb   = (bf16_t*)(ws);                       // 8192x1024   16MB (phase 1)
  bf16_t* AO   = (bf16_t*)(ws);                       // 8192x1024   16MB (phase 2, aliases Xb)
  bf16_t* Wqkv = (bf16_t*)(ws + (16l << 20));         // 1536x1024    3MB
  bf16_t* Wob  = (bf16_t*)(ws + (19l << 20));         // 1024x1024    2MB
  bf16_t* QKV  = (bf16_t*)(ws + (21l << 20));         // 8192x1536   24MB
  bf16_t* Vt   = (bf16_t*)(ws + (45l << 20));         // 2x256x4096   4MB

  const int M = 2 * S_LEN;  // 8192

  cvt_bf16<<<(M * DMODEL / 4 + 255) / 256, 256, 0, stream>>>((const float4*)X, Xb, M * DMODEL / 4);
  cvt_bf16<<<(DMODEL * DMODEL / 4 + 255) / 256, 256, 0, stream>>>((const float4*)Wq, Wqkv, DMODEL * DMODEL / 4);
  cvt_bf16<<<(DKV * DMODEL / 4 + 255) / 256, 256, 0, stream>>>((const float4*)Wk, Wqkv + 1024 * 1024, DKV * DMODEL / 4);
  cvt_bf16<<<(DKV * DMODEL / 4 + 255) / 256, 256, 0, stream>>>((const float4*)Wv, Wqkv + 1280 * 1024, DKV * DMODEL / 4);
  cvt_bf16<<<(DMODEL * DMODEL / 4 + 255) / 256, 256, 0, stream>>>((const float4*)Wo, Wob, DMODEL * DMODEL / 4);

  gemm_nt<bf16_t><<<dim3(M / 128, NQKV / 128), 256, 0, stream>>>(Xb, Wqkv, QKV, M, NQKV, DMODEL);
  transpose_v<<<dim3(S_LEN / 64, DKV / 64, 2), 256, 0, stream>>>(QKV, Vt);
  mla_attn<<<dim3(S_LEN / 64 * 8), 256, 0, stream>>>(QKV, Vt, AO);
  gemm_nt<float><<<dim3(M / 128, DMODEL / 128), 256, 0, stream>>>(AO, Wob, out, M, DMODEL, DMODEL);
}